// Round 11
// baseline (222.933 us; speedup 1.0000x reference)
//
#include <hip/hip_runtime.h>
#include <hip/hip_bf16.h>
#include <cstdint>

#define NN 1024
#define BBATCH 4
#define LLEN 12
#define NJ 384   // LLEN*32
#define TIDC 288
#define DIWC 7

typedef __attribute__((ext_vector_type(8))) short short8;
typedef __attribute__((ext_vector_type(4))) float f32x4;

typedef __attribute__((address_space(1))) const void* gas_ptr;
typedef __attribute__((address_space(3))) void* las_ptr;

__device__ inline ushort f2bf(float f) {
    unsigned u = __float_as_uint(f);
    u += 0x7FFFu + ((u >> 16) & 1u);
    return (ushort)(u >> 16);
}
__device__ inline float bf2f(ushort u) { return __uint_as_float(((unsigned)u) << 16); }

// ---------------- K_pre: merged adj-preprocess (bids 0..1023) + static support (1024..2047)
//                  + gate tables / weight transposes (2048..2378) ----------------
__global__ __launch_bounds__(256) void k_pre(const float* __restrict__ adj,
                                             ushort* __restrict__ adjF,
                                             ushort* __restrict__ adjT,
                                             float* __restrict__ rs,
                                             float* __restrict__ cs,
                                             const float* __restrict__ emb_u,
                                             const float* __restrict__ emb_d,
                                             ushort* __restrict__ S_bf,
                                             const float* __restrict__ W_g1,
                                             const float* __restrict__ b_g1,
                                             const float* __restrict__ TiD,
                                             const float* __restrict__ DiW,
                                             const float* __restrict__ W_st,
                                             const float* __restrict__ W_dif,
                                             float* __restrict__ U1,
                                             float* __restrict__ T1,
                                             float* __restrict__ D1,
                                             ushort* __restrict__ WstT_bf,
                                             ushort* __restrict__ WdT_bf) {
    __shared__ float smem[64 * 65];
    int bid = blockIdx.x;
    int t = threadIdx.x;
    if (bid < 1024) {
        float (*tile)[65] = (float(*)[65])smem;
        int b = bid >> 8;
        int r0 = ((bid >> 4) & 15) * 64, c0 = (bid & 15) * 64;
        int col = (t & 15) * 4, rb = t >> 4;
#pragma unroll
        for (int i = 0; i < 4; ++i) {
            int r = rb + i * 16;
            float4 v = *reinterpret_cast<const float4*>(&adj[((size_t)b * NN + r0 + r) * NN + c0 + col]);
            tile[r][col] = v.x; tile[r][col + 1] = v.y; tile[r][col + 2] = v.z; tile[r][col + 3] = v.w;
            unsigned lo = (unsigned)f2bf(v.x) | ((unsigned)f2bf(v.y) << 16);
            unsigned hi = (unsigned)f2bf(v.z) | ((unsigned)f2bf(v.w) << 16);
            *reinterpret_cast<uint2*>(&adjF[((size_t)b * NN + r0 + r) * NN + c0 + col]) = make_uint2(lo, hi);
        }
        __syncthreads();
        {
            int r4 = t >> 2, q4 = t & 3;
            float s1 = 0.f;
#pragma unroll
            for (int c = 0; c < 16; ++c) s1 += tile[r4][q4 * 16 + c];
            s1 += __shfl_xor(s1, 1, 64);
            s1 += __shfl_xor(s1, 2, 64);
            if (q4 == 0) atomicAdd(&rs[b * NN + r0 + r4], s1);
            float s2 = 0.f;
#pragma unroll
            for (int rr = 0; rr < 16; ++rr) s2 += tile[q4 * 16 + rr][r4];
            s2 += __shfl_xor(s2, 1, 64);
            s2 += __shfl_xor(s2, 2, 64);
            if (q4 == 0) atomicAdd(&cs[b * NN + c0 + r4], s2);
        }
        int j = t >> 2, ch = t & 3;
        short8 o0, o1;
#pragma unroll
        for (int q = 0; q < 8; ++q) o0[q] = (short)f2bf(tile[ch * 16 + q][j]);
#pragma unroll
        for (int q = 0; q < 8; ++q) o1[q] = (short)f2bf(tile[ch * 16 + 8 + q][j]);
        size_t orow = ((size_t)b * NN + c0 + j) * NN + r0 + ch * 16;
        *(short8*)&adjT[orow] = o0;
        *(short8*)&adjT[orow + 8] = o1;
    } else if (bid < 2048) {
        int i = bid - 1024;
        float* drow = smem;
        float* red = smem + 32;
        if (t < 32) drow[t] = emb_d[i * 32 + t];
        __syncthreads();
        float v[4];
        float lsum = 0.f;
        for (int jj = 0; jj < 4; ++jj) {
            int j = jj * 256 + t;
            const float4* u4 = reinterpret_cast<const float4*>(emb_u + (size_t)j * 32);
            float acc = 0.f;
#pragma unroll
            for (int k4 = 0; k4 < 8; ++k4) {
                float4 u = u4[k4];
                acc += drow[k4 * 4 + 0] * u.x + drow[k4 * 4 + 1] * u.y +
                       drow[k4 * 4 + 2] * u.z + drow[k4 * 4 + 3] * u.w;
            }
            acc = fmaxf(acc, 0.f);
            v[jj] = __expf(acc);
            lsum += v[jj];
        }
        red[t] = lsum;
        __syncthreads();
        for (int s = 128; s > 0; s >>= 1) {
            if (t < s) red[t] += red[t + s];
            __syncthreads();
        }
        float inv = 1.f / red[0];
        for (int jj = 0; jj < 4; ++jj) S_bf[(size_t)i * NN + jj * 256 + t] = f2bf(v[jj] * inv);
    } else {
        int r = (bid - 2048) * 4 + (t >> 6);
        int h = t & 63;
        if (r < NN) {
            float acc = b_g1[h];
            for (int i = 0; i < 32; ++i) acc = fmaf(emb_u[r * 32 + i], W_g1[(20 + i) * 64 + h], acc);
            for (int i = 0; i < 32; ++i) acc = fmaf(emb_d[r * 32 + i], W_g1[(52 + i) * 64 + h], acc);
            U1[r * 64 + h] = acc;
        } else if (r < NN + TIDC) {
            int tt = r - NN;
            float acc = 0.f;
            for (int i = 0; i < 10; ++i) acc = fmaf(TiD[tt * 10 + i], W_g1[i * 64 + h], acc);
            T1[tt * 64 + h] = acc;
        } else if (r < NN + TIDC + DIWC) {
            int dd = r - (NN + TIDC);
            float acc = 0.f;
            for (int i = 0; i < 10; ++i) acc = fmaf(DiW[dd * 10 + i], W_g1[(10 + i) * 64 + h], acc);
            D1[dd * 64 + h] = acc;
        } else if (r == NN + TIDC + DIWC) {
            for (int i = h; i < 32 * 96; i += 64) WstT_bf[i] = f2bf(W_st[(i % 96) * 32 + i / 96]);
        } else if (r == NN + TIDC + DIWC + 1) {
            for (int i = h; i < 32 * 224; i += 64) WdT_bf[i] = f2bf(W_dif[(i % 224) * 32 + i / 224]);
        }
    }
}

// ---------------- K3: fused H_st(MFMA) + H + gate + X_spa -> XT bf16 [b][j][n]  AND  out0(MFMA) ----------------
__global__ __launch_bounds__(256) void k_xspa(const float* __restrict__ hist,
                                              const float* __restrict__ hs,
                                              const float* __restrict__ W_emb,
                                              const float* __restrict__ b_emb,
                                              const float* __restrict__ b_st,
                                              const float* __restrict__ U1,
                                              const float* __restrict__ T1,
                                              const float* __restrict__ D1,
                                              const float* __restrict__ W_g2,
                                              const float* __restrict__ b_g2,
                                              const float* __restrict__ b_dif,
                                              const ushort* __restrict__ WstT_bf,
                                              const ushort* __restrict__ WdT_bf,
                                              ushort* __restrict__ XT,
                                              float* __restrict__ out) {
    __shared__ __align__(16) ushort hsm[64][104];    // [site][k<96], bf16
    __shared__ __align__(16) ushort Wst_s[32][104];  // [d][k<96]
    __shared__ __align__(16) ushort Hs_bf[64][40];   // [site][d<32]
    __shared__ __align__(16) ushort W0_s[32][40];    // [dout][j<32]
    __shared__ float gateL[64];
    __shared__ float histL[192];
    int t = threadIdx.x;
    int n0 = blockIdx.x * 64;
    int l = blockIdx.y;
    int b = blockIdx.z;
    for (int i = t; i < 384; i += 256) {
        int d = i / 12, c = i % 12;
        *(short8*)&Wst_s[d][c * 8] = *(const short8*)&WstT_bf[d * 96 + c * 8];
    }
    if (t < 128) {
        int d = t >> 2, c = t & 3;
        *(short8*)&W0_s[d][c * 8] = *(const short8*)&WdT_bf[d * 224 + c * 8];
    }
    if (t < 48)
        *(float4*)&histL[t * 4] =
            *(const float4*)&hist[(((size_t)b * LLEN + l) * NN + n0) * 3 + t * 4];
#pragma unroll
    for (int rr = 0; rr < 6; ++rr) {
        int i = t + 256 * rr;              // 0..1535 over (site, float4-chunk)
        int s = i / 24, c = i % 24;
        float4 v = *(const float4*)&hs[(((size_t)b * NN + n0 + s) * LLEN + l) * 96 + c * 4];
        ushort4 u;
        u.x = f2bf(v.x); u.y = f2bf(v.y); u.z = f2bf(v.z); u.w = f2bf(v.w);
        *(ushort4*)&hsm[s][c * 4] = u;
    }
    __syncthreads();
    // ---- gate phase: 64 sites x 4 lanes
    {
        int s = t >> 2, q = t & 3;
        int n = n0 + s;
        float x1 = histL[s * 3 + 1];
        float x2 = histL[s * 3 + 2] * (1.f / 7.f);
        int ti = (int)(x1 * 288.f); ti = ti < 0 ? 0 : (ti > 287 ? 287 : ti);
        int di = (int)(x2 * 7.f);   di = di < 0 ? 0 : (di > 6 ? 6 : di);
        const float* up = U1 + n * 64 + q * 16;
        const float* tp = T1 + ti * 64 + q * 16;
        const float* dp = D1 + di * 64 + q * 16;
        const float* wp = W_g2 + q * 16;
        float a = 0.f;
#pragma unroll
        for (int hh = 0; hh < 16; ++hh)
            a = fmaf(fmaxf(up[hh] + tp[hh] + dp[hh], 0.f), wp[hh], a);
        a += __shfl_xor(a, 1, 64);
        a += __shfl_xor(a, 2, 64);
        if (q == 0) gateL[s] = 1.f / (1.f + __expf(-(a + b_g2[0])));
    }
    // ---- MFMA H_st: M=64 sites (4 waves x 16), N=32 d, K=96
    int w = t >> 6, l6 = t & 63, lr = l6 & 15, lg = l6 >> 4;
    f32x4 hacc[2];
    hacc[0] = (f32x4){0.f, 0.f, 0.f, 0.f};
    hacc[1] = (f32x4){0.f, 0.f, 0.f, 0.f};
#pragma unroll
    for (int kc = 0; kc < 3; ++kc) {
        short8 a = *(const short8*)&hsm[w * 16 + lr][kc * 32 + lg * 8];
        short8 b0 = *(const short8*)&Wst_s[lr][kc * 32 + lg * 8];
        short8 b1 = *(const short8*)&Wst_s[16 + lr][kc * 32 + lg * 8];
        hacc[0] = __builtin_amdgcn_mfma_f32_16x16x32_bf16(a, b0, hacc[0], 0, 0, 0);
        hacc[1] = __builtin_amdgcn_mfma_f32_16x16x32_bf16(a, b1, hacc[1], 0, 0, 0);
    }
    // epilogue: H = relu(W_emb*x0 + b_emb + b_st + H_st) -> Hs_bf
#pragma unroll
    for (int h = 0; h < 2; ++h) {
        int d = h * 16 + lr;
        float we = W_emb[d];
        float bb = b_emb[d] + b_st[d];
#pragma unroll
        for (int r = 0; r < 4; ++r) {
            int s = w * 16 + lg * 4 + r;
            float v = fmaxf(fmaf(histL[s * 3], we, bb) + hacc[h][r], 0.f);
            Hs_bf[s][d] = f2bf(v);
        }
    }
    __syncthreads();
    // ---- MFMA out0: out = b_dif + gate * (H @ W_dif[0:32]), K=32
    f32x4 oacc[2];
    oacc[0] = (f32x4){0.f, 0.f, 0.f, 0.f};
    oacc[1] = (f32x4){0.f, 0.f, 0.f, 0.f};
    {
        short8 a = *(const short8*)&Hs_bf[w * 16 + lr][lg * 8];
        short8 b0 = *(const short8*)&W0_s[lr][lg * 8];
        short8 b1 = *(const short8*)&W0_s[16 + lr][lg * 8];
        oacc[0] = __builtin_amdgcn_mfma_f32_16x16x32_bf16(a, b0, oacc[0], 0, 0, 0);
        oacc[1] = __builtin_amdgcn_mfma_f32_16x16x32_bf16(a, b1, oacc[1], 0, 0, 0);
    }
#pragma unroll
    for (int h = 0; h < 2; ++h) {
        int d = h * 16 + lr;
        float bd = b_dif[d];
#pragma unroll
        for (int r = 0; r < 4; ++r) {
            int s = w * 16 + lg * 4 + r;
            out[(((size_t)b * LLEN + l) * NN + n0 + s) * 32 + d] = fmaf(gateL[s], oacc[h][r], bd);
        }
    }
    // ---- XT write
    {
        int dd = t >> 3, c = t & 7;
        short8 v;
#pragma unroll
        for (int i = 0; i < 8; ++i) {
            int s = c * 8 + i;
            v[i] = (short)f2bf(bf2f(Hs_bf[s][dd]) * gateL[s]);
        }
        *(short8*)&XT[((size_t)b * NJ + l * 32 + dd) * NN + n0 + c * 8] = v;
    }
}

// ---------------- K4: MFMA diffusion, BM=128 BN=64 BK=64, global_load_lds + 3-buffer counted-vmcnt ----------
// LDS slot [row][c] holds global chunk c^(row&7) (pre-swizzled source); reads use the same XOR.
#define STAGE(buf, kt)                                                              \
    {                                                                               \
        const ushort* gA = pA + (size_t)(kt) * 64;                                  \
        const ushort* gW = pW + (size_t)(kt) * 64;                                  \
        _Pragma("unroll") for (int i = 0; i < 4; ++i)                               \
            __builtin_amdgcn_global_load_lds(                                        \
                (gas_ptr)(gA + aoff[i]),                                             \
                (las_ptr)&As[buf][(w * 32 + i * 8) * 64], 16, 0, 0);                \
        _Pragma("unroll") for (int i = 0; i < 2; ++i)                               \
            __builtin_amdgcn_global_load_lds(                                        \
                (gas_ptr)(gW + woff[i]),                                             \
                (las_ptr)&Ws[buf][(w * 16 + i * 8) * 64], 16, 0, 0);                \
    }
#define DIFF_COMPUTE(buf)                                              \
    {                                                                  \
        _Pragma("unroll") for (int kk = 0; kk < 2; ++kk) {             \
            short8 af[4], bff[2];                                      \
            _Pragma("unroll") for (int mf = 0; mf < 4; ++mf) {         \
                int row = wm * 64 + mf * 16 + lr;                      \
                af[mf] = *(const short8*)&As[buf][row * 64 + (((kk * 4 + lg) ^ (row & 7)) * 8)]; \
            }                                                          \
            _Pragma("unroll") for (int nf = 0; nf < 2; ++nf) {         \
                int row = wn * 32 + nf * 16 + lr;                      \
                bff[nf] = *(const short8*)&Ws[buf][row * 64 + (((kk * 4 + lg) ^ (row & 7)) * 8)]; \
            }                                                          \
            _Pragma("unroll") for (int mf = 0; mf < 4; ++mf) {         \
                acc[mf][0] = __builtin_amdgcn_mfma_f32_16x16x32_bf16(af[mf], bff[0], acc[mf][0], 0, 0, 0); \
                acc[mf][1] = __builtin_amdgcn_mfma_f32_16x16x32_bf16(af[mf], bff[1], acc[mf][1], 0, 0, 0); \
            }                                                          \
        }                                                              \
    }

__global__ __launch_bounds__(256) void k_diff3(const ushort* __restrict__ S_bf,
                                               const ushort* __restrict__ adjF,
                                               const ushort* __restrict__ adjT,
                                               const float* __restrict__ rs,
                                               const float* __restrict__ cs,
                                               const ushort* __restrict__ In0,
                                               int in_per_chain,
                                               ushort* __restrict__ Out0) {
    __shared__ __align__(16) ushort As[3][128 * 64];   // 48 KB
    __shared__ __align__(16) ushort Ws[3][64 * 64];    // 24 KB  (72 KB total -> 2 blocks/CU)
    // bijective XCD swizzle over 576 blocks (72 per XCD); decode y-fastest within (x,z)
    int bid = blockIdx.x + 3 * blockIdx.y + 48 * blockIdx.z;
    int swz = (bid & 7) * 72 + (bid >> 3);
    int zz = swz / 48;
    int rem = swz % 48;
    int xx = rem >> 4, yy = rem & 15;
    int s = zz >> 2, b = zz & 3;
    int j0 = xx * 128;
    int n0 = yy * 64;
    const size_t ZT = (size_t)BBATCH * NJ * NN;
    const ushort* Wb = (s == 0) ? S_bf
                     : (s == 1) ? adjF + (size_t)b * NN * NN
                                : adjT + (size_t)b * NN * NN;
    const float* deg = (s == 0) ? nullptr : (s == 1 ? rs : cs);
    const ushort* Inb = In0 + (in_per_chain ? (size_t)s * ZT : 0) + (size_t)b * NJ * NN;
    ushort* Outb = Out0 + (size_t)s * ZT + (size_t)b * NJ * NN;

    int t = threadIdx.x;
    int w = t >> 6, wm = w >> 1, wn = w & 1;     // wave tile: 64j x 32n
    int l = t & 63, lr = l & 15, lg = l >> 4;
    // staging lane geometry: lane covers (row_local = l>>3, chunk = l&7), pre-swizzled source
    int rl = l >> 3, c8 = l & 7;
    size_t aoff[4], woff[2];
#pragma unroll
    for (int i = 0; i < 4; ++i) {
        int row = w * 32 + i * 8 + rl;
        aoff[i] = (size_t)row * NN + (size_t)((c8 ^ (row & 7)) * 8);
    }
#pragma unroll
    for (int i = 0; i < 2; ++i) {
        int row = w * 16 + i * 8 + rl;
        woff[i] = (size_t)row * NN + (size_t)((c8 ^ (row & 7)) * 8);
    }
    const ushort* pA = Inb + (size_t)j0 * NN;
    const ushort* pW = Wb + (size_t)n0 * NN;
    f32x4 acc[4][2];
#pragma unroll
    for (int i = 0; i < 4; ++i)
#pragma unroll
        for (int j = 0; j < 2; ++j) acc[i][j] = (f32x4){0.f, 0.f, 0.f, 0.f};

    // prologue: stage tiles 0 and 1; wait for tile 0 only (tile 1's 6 loads stay in flight)
    STAGE(0, 0);
    STAGE(1, 1);
    asm volatile("s_waitcnt vmcnt(6)" ::: "memory");
    __builtin_amdgcn_s_barrier();
    __builtin_amdgcn_sched_barrier(0);
#pragma unroll 1
    for (int kt = 0; kt < 14; ++kt) {
        STAGE((kt + 2) % 3, kt + 2);           // issue 2-ahead
        DIFF_COMPUTE(kt % 3);
        // tile kt+1 ready (keep kt+2's 6 loads in flight); barrier also guards
        // buffer (kt)%3 reuse by next iteration's STAGE.
        asm volatile("s_waitcnt vmcnt(6)" ::: "memory");
        __builtin_amdgcn_s_barrier();
        __builtin_amdgcn_sched_barrier(0);
    }
    DIFF_COMPUTE(2);                           // kt = 14 (14 % 3 == 2)
    asm volatile("s_waitcnt vmcnt(0)" ::: "memory");
    __builtin_amdgcn_s_barrier();
    __builtin_amdgcn_sched_barrier(0);
    DIFF_COMPUTE(0);                           // kt = 15 (15 % 3 == 0)

    bool resid = (deg != nullptr);
#pragma unroll
    for (int nf = 0; nf < 2; ++nf) {
        int n_g = n0 + wn * 32 + nf * 16 + lr;
        float scale = 1.f;
        if (resid) scale = 1.f / (deg[b * NN + n_g] + 1.f);
#pragma unroll
        for (int mf = 0; mf < 4; ++mf) {
#pragma unroll
            for (int r = 0; r < 4; ++r) {
                int j_g = j0 + wm * 64 + mf * 16 + lg * 4 + r;
                float v = acc[mf][nf][r];
                if (resid) v += bf2f(Inb[(size_t)j_g * NN + n_g]);
                v *= scale;
                Outb[(size_t)j_g * NN + n_g] = f2bf(v);
            }
        }
    }
}

// ---------------- K5: out += Zcat @ W_dif[32:224] via MFMA; M=64 sites, N=32 d, K=192 ----------------
__global__ __launch_bounds__(256) void k_zmfma(const ushort* __restrict__ Z1,
                                               const ushort* __restrict__ Z2,
                                               const ushort* __restrict__ WdT_bf,
                                               float* __restrict__ out) {
    __shared__ __align__(16) ushort zT[64][200];    // [site][k<192]
    __shared__ __align__(16) ushort Wd_s[32][200];  // [d][k<192] = W_difT rows, k offset 32
    const size_t ZT = (size_t)BBATCH * NJ * NN;
    int t = threadIdx.x;
    int n0 = blockIdx.x * 64;
    int l = blockIdx.y;
    int b = blockIdx.z;
    for (int i = t; i < 768; i += 256) {
        int d = i / 24, c = i % 24;
        *(short8*)&Wd_s[d][c * 8] = *(const short8*)&WdT_bf[d * 224 + 32 + c * 8];
    }
    {
        int j = t >> 3, ch = t & 7;
#pragma unroll
        for (int c = 0; c < 6; ++c) {
            const ushort* Zp = ((c & 1) ? Z2 : Z1) + (size_t)(c >> 1) * ZT;
            short8 v = *(const short8*)&Zp[((size_t)b * NJ + l * 32 + j) * NN + n0 + ch * 8];
#pragma unroll
            for (int q = 0; q < 8; ++q) zT[ch * 8 + q][c * 32 + j] = (ushort)v[q];
        }
    }
    __syncthreads();
    int w = t >> 6, l6 = t & 63, lr = l6 & 15, lg = l6 >> 4;
    f32x4 acc[2];
    acc[0] = (f32x4){0.f, 0.f, 0.f, 0.f};
    acc[1] = (f32x4){0.f, 0.f, 0.f, 0.f};
#pragma unroll
    for (int kc = 0; kc < 6; ++kc) {
        short8 a = *(const short8*)&zT[w * 16 + lr][kc * 32 + lg * 8];
        short8 b0 = *(const short8*)&Wd_s[lr][kc * 32 + lg * 8];
        short8 b1 = *(const short8*)&Wd_s[16 + lr][kc * 32 + lg * 8];
        acc[0] = __builtin_amdgcn_mfma_f32_16x16x32_bf16(a, b0, acc[0], 0, 0, 0);
        acc[1] = __builtin_amdgcn_mfma_f32_16x16x32_bf16(a, b1, acc[1], 0, 0, 0);
    }
#pragma unroll
    for (int h = 0; h < 2; ++h) {
        int d = h * 16 + lr;
#pragma unroll
        for (int r = 0; r < 4; ++r) {
            int s = w * 16 + lg * 4 + r;
            size_t oi = (((size_t)b * LLEN + l) * NN + n0 + s) * 32 + d;
            out[oi] += acc[h][r];
        }
    }
}

extern "C" void kernel_launch(void* const* d_in, const int* in_sizes, int n_in,
                              void* d_out, int out_size, void* d_ws, size_t ws_size,
                              hipStream_t stream) {
    (void)in_sizes; (void)n_in; (void)out_size; (void)ws_size;
    const float* hist  = (const float*)d_in[0];
    const float* hs    = (const float*)d_in[1];
    const float* adj   = (const float*)d_in[2];
    const float* W_emb = (const float*)d_in[3];
    const float* b_emb = (const float*)d_in[4];
    const float* W_st  = (const float*)d_in[5];
    const float* b_st  = (const float*)d_in[6];
    const float* TiD   = (const float*)d_in[7];
    const float* DiW   = (const float*)d_in[8];
    const float* emb_u = (const float*)d_in[9];
    const float* emb_d = (const float*)d_in[10];
    const float* W_g1  = (const float*)d_in[11];
    const float* b_g1  = (const float*)d_in[12];
    const float* W_g2  = (const float*)d_in[13];
    const float* b_g2  = (const float*)d_in[14];
    const float* W_dif = (const float*)d_in[15];
    const float* b_dif = (const float*)d_in[16];
    float* out = (float*)d_out;

    // ws layout (bytes), total ~39.4 MB (ws_size ~268 MB per fill evidence)
    uint8_t* w8 = (uint8_t*)d_ws;
    ushort* adjF = (ushort*)w8;                      // 8 MB  adj bf16 [b][n][k]
    ushort* adjT = (ushort*)(w8 + 8388608);          // 8 MB  adj^T bf16 [b][n][k]
    ushort* S_bf = (ushort*)(w8 + 16777216);         // 2 MB
    ushort* XT   = (ushort*)(w8 + 18874368);         // 3 MB  [b][384][1024]
    ushort* Z1   = (ushort*)(w8 + 22020096);         // 9 MB  [s][b][384][1024]
    ushort* Z2   = (ushort*)(w8 + 31457280);         // 9 MB
    float*  rs   = (float*)(w8 + 40894464);          // 16 KB
    float*  cs   = (float*)(w8 + 40910848);          // 16 KB (contiguous with rs)
    float*  U1   = (float*)(w8 + 40927232);          // 256 KB
    float*  T1   = (float*)(w8 + 41189376);          // 72 KB
    float*  D1   = (float*)(w8 + 41263104);          // 1.8 KB
    ushort* WstT_bf = (ushort*)(w8 + 41264896);      // 6 KB  [32][96]
    ushort* WdT_bf  = (ushort*)(w8 + 41271040);      // 14 KB [32][224]

    hipMemsetAsync(rs, 0, 2 * BBATCH * NN * sizeof(float), stream);   // rs + cs
    k_pre<<<2379, 256, 0, stream>>>(adj, adjF, adjT, rs, cs, emb_u, emb_d, S_bf,
                                    W_g1, b_g1, TiD, DiW, W_st, W_dif,
                                    U1, T1, D1, WstT_bf, WdT_bf);
    k_xspa<<<dim3(16, 12, 4), 256, 0, stream>>>(hist, hs, W_emb, b_emb, b_st, U1, T1, D1,
                                                W_g2, b_g2, b_dif, WstT_bf, WdT_bf, XT, out);
    dim3 dgrid(3, 16, 12);
    k_diff3<<<dgrid, 256, 0, stream>>>(S_bf, adjF, adjT, rs, cs, XT, 0, Z1);
    k_diff3<<<dgrid, 256, 0, stream>>>(S_bf, adjF, adjT, rs, cs, Z1, 1, Z2);
    k_zmfma<<<dim3(16, 12, 4), 256, 0, stream>>>(Z1, Z2, WdT_bf, out);
}

// Round 12
// 194.367 us; speedup vs baseline: 1.1470x; 1.1470x over previous
//
#include <hip/hip_runtime.h>
#include <hip/hip_bf16.h>
#include <cstdint>

#define NN 1024
#define BBATCH 4
#define LLEN 12
#define NJ 384   // LLEN*32
#define TIDC 288
#define DIWC 7

typedef __attribute__((ext_vector_type(8))) short short8;
typedef __attribute__((ext_vector_type(4))) float f32x4;

typedef __attribute__((address_space(1))) const void* gas_ptr;
typedef __attribute__((address_space(3))) void* las_ptr;

__device__ inline ushort f2bf(float f) {
    unsigned u = __float_as_uint(f);
    u += 0x7FFFu + ((u >> 16) & 1u);
    return (ushort)(u >> 16);
}
__device__ inline float bf2f(ushort u) { return __uint_as_float(((unsigned)u) << 16); }

// ---------------- K_pre: merged adj-preprocess (bids 0..1023) + static support (1024..2047)
//                  + gate tables / weight transposes (2048..2378) ----------------
__global__ __launch_bounds__(256) void k_pre(const float* __restrict__ adj,
                                             ushort* __restrict__ adjF,
                                             ushort* __restrict__ adjT,
                                             float* __restrict__ rs,
                                             float* __restrict__ cs,
                                             const float* __restrict__ emb_u,
                                             const float* __restrict__ emb_d,
                                             ushort* __restrict__ S_bf,
                                             const float* __restrict__ W_g1,
                                             const float* __restrict__ b_g1,
                                             const float* __restrict__ TiD,
                                             const float* __restrict__ DiW,
                                             const float* __restrict__ W_st,
                                             const float* __restrict__ W_dif,
                                             float* __restrict__ U1,
                                             float* __restrict__ T1,
                                             float* __restrict__ D1,
                                             ushort* __restrict__ WstT_bf,
                                             ushort* __restrict__ WdT_bf) {
    __shared__ float smem[64 * 65];
    int bid = blockIdx.x;
    int t = threadIdx.x;
    if (bid < 1024) {
        float (*tile)[65] = (float(*)[65])smem;
        int b = bid >> 8;
        int r0 = ((bid >> 4) & 15) * 64, c0 = (bid & 15) * 64;
        int col = (t & 15) * 4, rb = t >> 4;
#pragma unroll
        for (int i = 0; i < 4; ++i) {
            int r = rb + i * 16;
            float4 v = *reinterpret_cast<const float4*>(&adj[((size_t)b * NN + r0 + r) * NN + c0 + col]);
            tile[r][col] = v.x; tile[r][col + 1] = v.y; tile[r][col + 2] = v.z; tile[r][col + 3] = v.w;
            unsigned lo = (unsigned)f2bf(v.x) | ((unsigned)f2bf(v.y) << 16);
            unsigned hi = (unsigned)f2bf(v.z) | ((unsigned)f2bf(v.w) << 16);
            *reinterpret_cast<uint2*>(&adjF[((size_t)b * NN + r0 + r) * NN + c0 + col]) = make_uint2(lo, hi);
        }
        __syncthreads();
        {
            int r4 = t >> 2, q4 = t & 3;
            float s1 = 0.f;
#pragma unroll
            for (int c = 0; c < 16; ++c) s1 += tile[r4][q4 * 16 + c];
            s1 += __shfl_xor(s1, 1, 64);
            s1 += __shfl_xor(s1, 2, 64);
            if (q4 == 0) atomicAdd(&rs[b * NN + r0 + r4], s1);
            float s2 = 0.f;
#pragma unroll
            for (int rr = 0; rr < 16; ++rr) s2 += tile[q4 * 16 + rr][r4];
            s2 += __shfl_xor(s2, 1, 64);
            s2 += __shfl_xor(s2, 2, 64);
            if (q4 == 0) atomicAdd(&cs[b * NN + c0 + r4], s2);
        }
        int j = t >> 2, ch = t & 3;
        short8 o0, o1;
#pragma unroll
        for (int q = 0; q < 8; ++q) o0[q] = (short)f2bf(tile[ch * 16 + q][j]);
#pragma unroll
        for (int q = 0; q < 8; ++q) o1[q] = (short)f2bf(tile[ch * 16 + 8 + q][j]);
        size_t orow = ((size_t)b * NN + c0 + j) * NN + r0 + ch * 16;
        *(short8*)&adjT[orow] = o0;
        *(short8*)&adjT[orow + 8] = o1;
    } else if (bid < 2048) {
        int i = bid - 1024;
        float* drow = smem;
        float* red = smem + 32;
        if (t < 32) drow[t] = emb_d[i * 32 + t];
        __syncthreads();
        float v[4];
        float lsum = 0.f;
        for (int jj = 0; jj < 4; ++jj) {
            int j = jj * 256 + t;
            const float4* u4 = reinterpret_cast<const float4*>(emb_u + (size_t)j * 32);
            float acc = 0.f;
#pragma unroll
            for (int k4 = 0; k4 < 8; ++k4) {
                float4 u = u4[k4];
                acc += drow[k4 * 4 + 0] * u.x + drow[k4 * 4 + 1] * u.y +
                       drow[k4 * 4 + 2] * u.z + drow[k4 * 4 + 3] * u.w;
            }
            acc = fmaxf(acc, 0.f);
            v[jj] = __expf(acc);
            lsum += v[jj];
        }
        red[t] = lsum;
        __syncthreads();
        for (int s = 128; s > 0; s >>= 1) {
            if (t < s) red[t] += red[t + s];
            __syncthreads();
        }
        float inv = 1.f / red[0];
        for (int jj = 0; jj < 4; ++jj) S_bf[(size_t)i * NN + jj * 256 + t] = f2bf(v[jj] * inv);
    } else {
        int r = (bid - 2048) * 4 + (t >> 6);
        int h = t & 63;
        if (r < NN) {
            float acc = b_g1[h];
            for (int i = 0; i < 32; ++i) acc = fmaf(emb_u[r * 32 + i], W_g1[(20 + i) * 64 + h], acc);
            for (int i = 0; i < 32; ++i) acc = fmaf(emb_d[r * 32 + i], W_g1[(52 + i) * 64 + h], acc);
            U1[r * 64 + h] = acc;
        } else if (r < NN + TIDC) {
            int tt = r - NN;
            float acc = 0.f;
            for (int i = 0; i < 10; ++i) acc = fmaf(TiD[tt * 10 + i], W_g1[i * 64 + h], acc);
            T1[tt * 64 + h] = acc;
        } else if (r < NN + TIDC + DIWC) {
            int dd = r - (NN + TIDC);
            float acc = 0.f;
            for (int i = 0; i < 10; ++i) acc = fmaf(DiW[dd * 10 + i], W_g1[(10 + i) * 64 + h], acc);
            D1[dd * 64 + h] = acc;
        } else if (r == NN + TIDC + DIWC) {
            for (int i = h; i < 32 * 96; i += 64) WstT_bf[i] = f2bf(W_st[(i % 96) * 32 + i / 96]);
        } else if (r == NN + TIDC + DIWC + 1) {
            for (int i = h; i < 32 * 224; i += 64) WdT_bf[i] = f2bf(W_dif[(i % 224) * 32 + i / 224]);
        }
    }
}

// ---------------- K3: fused H_st(MFMA) + H + gate + X_spa -> XT bf16 [b][j][n]  AND  out0(MFMA) ----------------
__global__ __launch_bounds__(256) void k_xspa(const float* __restrict__ hist,
                                              const float* __restrict__ hs,
                                              const float* __restrict__ W_emb,
                                              const float* __restrict__ b_emb,
                                              const float* __restrict__ b_st,
                                              const float* __restrict__ U1,
                                              const float* __restrict__ T1,
                                              const float* __restrict__ D1,
                                              const float* __restrict__ W_g2,
                                              const float* __restrict__ b_g2,
                                              const float* __restrict__ b_dif,
                                              const ushort* __restrict__ WstT_bf,
                                              const ushort* __restrict__ WdT_bf,
                                              ushort* __restrict__ XT,
                                              float* __restrict__ out) {
    __shared__ __align__(16) ushort hsm[64][104];    // [site][k<96], bf16
    __shared__ __align__(16) ushort Wst_s[32][104];  // [d][k<96]
    __shared__ __align__(16) ushort Hs_bf[64][40];   // [site][d<32]
    __shared__ __align__(16) ushort W0_s[32][40];    // [dout][j<32]
    __shared__ float gateL[64];
    __shared__ float histL[192];
    int t = threadIdx.x;
    int n0 = blockIdx.x * 64;
    int l = blockIdx.y;
    int b = blockIdx.z;
    for (int i = t; i < 384; i += 256) {
        int d = i / 12, c = i % 12;
        *(short8*)&Wst_s[d][c * 8] = *(const short8*)&WstT_bf[d * 96 + c * 8];
    }
    if (t < 128) {
        int d = t >> 2, c = t & 3;
        *(short8*)&W0_s[d][c * 8] = *(const short8*)&WdT_bf[d * 224 + c * 8];
    }
    if (t < 48)
        *(float4*)&histL[t * 4] =
            *(const float4*)&hist[(((size_t)b * LLEN + l) * NN + n0) * 3 + t * 4];
#pragma unroll
    for (int rr = 0; rr < 6; ++rr) {
        int i = t + 256 * rr;              // 0..1535 over (site, float4-chunk)
        int s = i / 24, c = i % 24;
        float4 v = *(const float4*)&hs[(((size_t)b * NN + n0 + s) * LLEN + l) * 96 + c * 4];
        ushort4 u;
        u.x = f2bf(v.x); u.y = f2bf(v.y); u.z = f2bf(v.z); u.w = f2bf(v.w);
        *(ushort4*)&hsm[s][c * 4] = u;
    }
    __syncthreads();
    // ---- gate phase: 64 sites x 4 lanes
    {
        int s = t >> 2, q = t & 3;
        int n = n0 + s;
        float x1 = histL[s * 3 + 1];
        float x2 = histL[s * 3 + 2] * (1.f / 7.f);
        int ti = (int)(x1 * 288.f); ti = ti < 0 ? 0 : (ti > 287 ? 287 : ti);
        int di = (int)(x2 * 7.f);   di = di < 0 ? 0 : (di > 6 ? 6 : di);
        const float* up = U1 + n * 64 + q * 16;
        const float* tp = T1 + ti * 64 + q * 16;
        const float* dp = D1 + di * 64 + q * 16;
        const float* wp = W_g2 + q * 16;
        float a = 0.f;
#pragma unroll
        for (int hh = 0; hh < 16; ++hh)
            a = fmaf(fmaxf(up[hh] + tp[hh] + dp[hh], 0.f), wp[hh], a);
        a += __shfl_xor(a, 1, 64);
        a += __shfl_xor(a, 2, 64);
        if (q == 0) gateL[s] = 1.f / (1.f + __expf(-(a + b_g2[0])));
    }
    // ---- MFMA H_st: M=64 sites (4 waves x 16), N=32 d, K=96
    int w = t >> 6, l6 = t & 63, lr = l6 & 15, lg = l6 >> 4;
    f32x4 hacc[2];
    hacc[0] = (f32x4){0.f, 0.f, 0.f, 0.f};
    hacc[1] = (f32x4){0.f, 0.f, 0.f, 0.f};
#pragma unroll
    for (int kc = 0; kc < 3; ++kc) {
        short8 a = *(const short8*)&hsm[w * 16 + lr][kc * 32 + lg * 8];
        short8 b0 = *(const short8*)&Wst_s[lr][kc * 32 + lg * 8];
        short8 b1 = *(const short8*)&Wst_s[16 + lr][kc * 32 + lg * 8];
        hacc[0] = __builtin_amdgcn_mfma_f32_16x16x32_bf16(a, b0, hacc[0], 0, 0, 0);
        hacc[1] = __builtin_amdgcn_mfma_f32_16x16x32_bf16(a, b1, hacc[1], 0, 0, 0);
    }
    // epilogue: H = relu(W_emb*x0 + b_emb + b_st + H_st) -> Hs_bf
#pragma unroll
    for (int h = 0; h < 2; ++h) {
        int d = h * 16 + lr;
        float we = W_emb[d];
        float bb = b_emb[d] + b_st[d];
#pragma unroll
        for (int r = 0; r < 4; ++r) {
            int s = w * 16 + lg * 4 + r;
            float v = fmaxf(fmaf(histL[s * 3], we, bb) + hacc[h][r], 0.f);
            Hs_bf[s][d] = f2bf(v);
        }
    }
    __syncthreads();
    // ---- MFMA out0: out = b_dif + gate * (H @ W_dif[0:32]), K=32
    f32x4 oacc[2];
    oacc[0] = (f32x4){0.f, 0.f, 0.f, 0.f};
    oacc[1] = (f32x4){0.f, 0.f, 0.f, 0.f};
    {
        short8 a = *(const short8*)&Hs_bf[w * 16 + lr][lg * 8];
        short8 b0 = *(const short8*)&W0_s[lr][lg * 8];
        short8 b1 = *(const short8*)&W0_s[16 + lr][lg * 8];
        oacc[0] = __builtin_amdgcn_mfma_f32_16x16x32_bf16(a, b0, oacc[0], 0, 0, 0);
        oacc[1] = __builtin_amdgcn_mfma_f32_16x16x32_bf16(a, b1, oacc[1], 0, 0, 0);
    }
#pragma unroll
    for (int h = 0; h < 2; ++h) {
        int d = h * 16 + lr;
        float bd = b_dif[d];
#pragma unroll
        for (int r = 0; r < 4; ++r) {
            int s = w * 16 + lg * 4 + r;
            out[(((size_t)b * LLEN + l) * NN + n0 + s) * 32 + d] = fmaf(gateL[s], oacc[h][r], bd);
        }
    }
    // ---- XT write
    {
        int dd = t >> 3, c = t & 7;
        short8 v;
#pragma unroll
        for (int i = 0; i < 8; ++i) {
            int s = c * 8 + i;
            v[i] = (short)f2bf(bf2f(Hs_bf[s][dd]) * gateL[s]);
        }
        *(short8*)&XT[((size_t)b * NJ + l * 32 + dd) * NN + n0 + c * 8] = v;
    }
}

// ---------------- K4: MFMA diffusion, BM=128 BN=64 BK=64, global_load_lds, 2-buffer counted-vmcnt ----------
// LDS slot [row][c] holds global chunk c^(row&7) (pre-swizzled source); reads use the same XOR.
#define STAGE(buf, kt)                                                              \
    {                                                                               \
        const ushort* gA = pA + (size_t)(kt) * 64;                                  \
        const ushort* gW = pW + (size_t)(kt) * 64;                                  \
        _Pragma("unroll") for (int i = 0; i < 4; ++i)                               \
            __builtin_amdgcn_global_load_lds(                                        \
                (gas_ptr)(gA + aoff[i]),                                             \
                (las_ptr)&As[buf][(w * 32 + i * 8) * 64], 16, 0, 0);                \
        _Pragma("unroll") for (int i = 0; i < 2; ++i)                               \
            __builtin_amdgcn_global_load_lds(                                        \
                (gas_ptr)(gW + woff[i]),                                             \
                (las_ptr)&Ws[buf][(w * 16 + i * 8) * 64], 16, 0, 0);                \
    }
#define DIFF_COMPUTE(buf)                                              \
    {                                                                  \
        _Pragma("unroll") for (int kk = 0; kk < 2; ++kk) {             \
            short8 af[4], bff[2];                                      \
            _Pragma("unroll") for (int mf = 0; mf < 4; ++mf) {         \
                int row = wm * 64 + mf * 16 + lr;                      \
                af[mf] = *(const short8*)&As[buf][row * 64 + (((kk * 4 + lg) ^ (row & 7)) * 8)]; \
            }                                                          \
            _Pragma("unroll") for (int nf = 0; nf < 2; ++nf) {         \
                int row = wn * 32 + nf * 16 + lr;                      \
                bff[nf] = *(const short8*)&Ws[buf][row * 64 + (((kk * 4 + lg) ^ (row & 7)) * 8)]; \
            }                                                          \
            _Pragma("unroll") for (int mf = 0; mf < 4; ++mf) {         \
                acc[mf][0] = __builtin_amdgcn_mfma_f32_16x16x32_bf16(af[mf], bff[0], acc[mf][0], 0, 0, 0); \
                acc[mf][1] = __builtin_amdgcn_mfma_f32_16x16x32_bf16(af[mf], bff[1], acc[mf][1], 0, 0, 0); \
            }                                                          \
        }                                                              \
    }

__global__ __launch_bounds__(256) void k_diff3(const ushort* __restrict__ S_bf,
                                               const ushort* __restrict__ adjF,
                                               const ushort* __restrict__ adjT,
                                               const float* __restrict__ rs,
                                               const float* __restrict__ cs,
                                               const ushort* __restrict__ In0,
                                               int in_per_chain,
                                               ushort* __restrict__ Out0) {
    __shared__ __align__(16) ushort As[2][128 * 64];   // 32 KB
    __shared__ __align__(16) ushort Ws[2][64 * 64];    // 16 KB  (48 KB total -> 3 blocks/CU)
    // bijective XCD swizzle over 576 blocks (72 per XCD); decode y-fastest within (x,z)
    int bid = blockIdx.x + 3 * blockIdx.y + 48 * blockIdx.z;
    int swz = (bid & 7) * 72 + (bid >> 3);
    int zz = swz / 48;
    int rem = swz % 48;
    int xx = rem >> 4, yy = rem & 15;
    int s = zz >> 2, b = zz & 3;
    int j0 = xx * 128;
    int n0 = yy * 64;
    const size_t ZT = (size_t)BBATCH * NJ * NN;
    const ushort* Wb = (s == 0) ? S_bf
                     : (s == 1) ? adjF + (size_t)b * NN * NN
                                : adjT + (size_t)b * NN * NN;
    const float* deg = (s == 0) ? nullptr : (s == 1 ? rs : cs);
    const ushort* Inb = In0 + (in_per_chain ? (size_t)s * ZT : 0) + (size_t)b * NJ * NN;
    ushort* Outb = Out0 + (size_t)s * ZT + (size_t)b * NJ * NN;

    int t = threadIdx.x;
    int w = t >> 6, wm = w >> 1, wn = w & 1;     // wave tile: 64j x 32n
    int l = t & 63, lr = l & 15, lg = l >> 4;
    // staging lane geometry: lane covers (row_local = l>>3, chunk = l&7), pre-swizzled source
    int rl = l >> 3, c8 = l & 7;
    size_t aoff[4], woff[2];
#pragma unroll
    for (int i = 0; i < 4; ++i) {
        int row = w * 32 + i * 8 + rl;
        aoff[i] = (size_t)row * NN + (size_t)((c8 ^ (row & 7)) * 8);
    }
#pragma unroll
    for (int i = 0; i < 2; ++i) {
        int row = w * 16 + i * 8 + rl;
        woff[i] = (size_t)row * NN + (size_t)((c8 ^ (row & 7)) * 8);
    }
    const ushort* pA = Inb + (size_t)j0 * NN;
    const ushort* pW = Wb + (size_t)n0 * NN;
    f32x4 acc[4][2];
#pragma unroll
    for (int i = 0; i < 4; ++i)
#pragma unroll
        for (int j = 0; j < 2; ++j) acc[i][j] = (f32x4){0.f, 0.f, 0.f, 0.f};

    // 2-buffer counted-vmcnt pipeline:
    //   iter kt: STAGE(buf^1 <- tile kt+1) ; vmcnt(6) [tile kt landed, 6 newest in flight]
    //            ; s_barrier [all waves' tile-kt loads landed] ; COMPUTE(buf)
    //            ; s_barrier [protect buf from next iter's STAGE overwrite]
    STAGE(0, 0);
    int cur = 0;
#pragma unroll 1
    for (int kt = 0; kt < 16; ++kt) {
        if (kt < 15) {
            STAGE(cur ^ 1, kt + 1);
            asm volatile("s_waitcnt vmcnt(6)" ::: "memory");
        } else {
            asm volatile("s_waitcnt vmcnt(0)" ::: "memory");
        }
        __builtin_amdgcn_s_barrier();
        __builtin_amdgcn_sched_barrier(0);
        DIFF_COMPUTE(cur);
        __builtin_amdgcn_s_barrier();
        cur ^= 1;
    }

    bool resid = (deg != nullptr);
#pragma unroll
    for (int nf = 0; nf < 2; ++nf) {
        int n_g = n0 + wn * 32 + nf * 16 + lr;
        float scale = 1.f;
        if (resid) scale = 1.f / (deg[b * NN + n_g] + 1.f);
#pragma unroll
        for (int mf = 0; mf < 4; ++mf) {
#pragma unroll
            for (int r = 0; r < 4; ++r) {
                int j_g = j0 + wm * 64 + mf * 16 + lg * 4 + r;
                float v = acc[mf][nf][r];
                if (resid) v += bf2f(Inb[(size_t)j_g * NN + n_g]);
                v *= scale;
                Outb[(size_t)j_g * NN + n_g] = f2bf(v);
            }
        }
    }
}

// ---------------- K5: out += Zcat @ W_dif[32:224] via MFMA; M=64 sites, N=32 d, K=192 ----------------
__global__ __launch_bounds__(256) void k_zmfma(const ushort* __restrict__ Z1,
                                               const ushort* __restrict__ Z2,
                                               const ushort* __restrict__ WdT_bf,
                                               float* __restrict__ out) {
    __shared__ __align__(16) ushort zT[64][200];    // [site][k<192]
    __shared__ __align__(16) ushort Wd_s[32][200];  // [d][k<192] = W_difT rows, k offset 32
    const size_t ZT = (size_t)BBATCH * NJ * NN;
    int t = threadIdx.x;
    int n0 = blockIdx.x * 64;
    int l = blockIdx.y;
    int b = blockIdx.z;
    for (int i = t; i < 768; i += 256) {
        int d = i / 24, c = i % 24;
        *(short8*)&Wd_s[d][c * 8] = *(const short8*)&WdT_bf[d * 224 + 32 + c * 8];
    }
    {
        int j = t >> 3, ch = t & 7;
#pragma unroll
        for (int c = 0; c < 6; ++c) {
            const ushort* Zp = ((c & 1) ? Z2 : Z1) + (size_t)(c >> 1) * ZT;
            short8 v = *(const short8*)&Zp[((size_t)b * NJ + l * 32 + j) * NN + n0 + ch * 8];
#pragma unroll
            for (int q = 0; q < 8; ++q) zT[ch * 8 + q][c * 32 + j] = (ushort)v[q];
        }
    }
    __syncthreads();
    int w = t >> 6, l6 = t & 63, lr = l6 & 15, lg = l6 >> 4;
    f32x4 acc[2];
    acc[0] = (f32x4){0.f, 0.f, 0.f, 0.f};
    acc[1] = (f32x4){0.f, 0.f, 0.f, 0.f};
#pragma unroll
    for (int kc = 0; kc < 6; ++kc) {
        short8 a = *(const short8*)&zT[w * 16 + lr][kc * 32 + lg * 8];
        short8 b0 = *(const short8*)&Wd_s[lr][kc * 32 + lg * 8];
        short8 b1 = *(const short8*)&Wd_s[16 + lr][kc * 32 + lg * 8];
        acc[0] = __builtin_amdgcn_mfma_f32_16x16x32_bf16(a, b0, acc[0], 0, 0, 0);
        acc[1] = __builtin_amdgcn_mfma_f32_16x16x32_bf16(a, b1, acc[1], 0, 0, 0);
    }
#pragma unroll
    for (int h = 0; h < 2; ++h) {
        int d = h * 16 + lr;
#pragma unroll
        for (int r = 0; r < 4; ++r) {
            int s = w * 16 + lg * 4 + r;
            size_t oi = (((size_t)b * LLEN + l) * NN + n0 + s) * 32 + d;
            out[oi] += acc[h][r];
        }
    }
}

extern "C" void kernel_launch(void* const* d_in, const int* in_sizes, int n_in,
                              void* d_out, int out_size, void* d_ws, size_t ws_size,
                              hipStream_t stream) {
    (void)in_sizes; (void)n_in; (void)out_size; (void)ws_size;
    const float* hist  = (const float*)d_in[0];
    const float* hs    = (const float*)d_in[1];
    const float* adj   = (const float*)d_in[2];
    const float* W_emb = (const float*)d_in[3];
    const float* b_emb = (const float*)d_in[4];
    const float* W_st  = (const float*)d_in[5];
    const float* b_st  = (const float*)d_in[6];
    const float* TiD   = (const float*)d_in[7];
    const float* DiW   = (const float*)d_in[8];
    const float* emb_u = (const float*)d_in[9];
    const float* emb_d = (const float*)d_in[10];
    const float* W_g1  = (const float*)d_in[11];
    const float* b_g1  = (const float*)d_in[12];
    const float* W_g2  = (const float*)d_in[13];
    const float* b_g2  = (const float*)d_in[14];
    const float* W_dif = (const float*)d_in[15];
    const float* b_dif = (const float*)d_in[16];
    float* out = (float*)d_out;

    // ws layout (bytes), total ~39.4 MB (ws_size ~268 MB per fill evidence)
    uint8_t* w8 = (uint8_t*)d_ws;
    ushort* adjF = (ushort*)w8;                      // 8 MB  adj bf16 [b][n][k]
    ushort* adjT = (ushort*)(w8 + 8388608);          // 8 MB  adj^T bf16 [b][n][k]
    ushort* S_bf = (ushort*)(w8 + 16777216);         // 2 MB
    ushort* XT   = (ushort*)(w8 + 18874368);         // 3 MB  [b][384][1024]
    ushort* Z1   = (ushort*)(w8 + 22020096);         // 9 MB  [s][b][384][1024]
    ushort* Z2   = (ushort*)(w8 + 31457280);         // 9 MB
    float*  rs   = (float*)(w8 + 40894464);          // 16 KB
    float*  cs   = (float*)(w8 + 40910848);          // 16 KB (contiguous with rs)
    float*  U1   = (float*)(w8 + 40927232);          // 256 KB
    float*  T1   = (float*)(w8 + 41189376);          // 72 KB
    float*  D1   = (float*)(w8 + 41263104);          // 1.8 KB
    ushort* WstT_bf = (ushort*)(w8 + 41264896);      // 6 KB  [32][96]
    ushort* WdT_bf  = (ushort*)(w8 + 41271040);      // 14 KB [32][224]

    hipMemsetAsync(rs, 0, 2 * BBATCH * NN * sizeof(float), stream);   // rs + cs
    k_pre<<<2379, 256, 0, stream>>>(adj, adjF, adjT, rs, cs, emb_u, emb_d, S_bf,
                                    W_g1, b_g1, TiD, DiW, W_st, W_dif,
                                    U1, T1, D1, WstT_bf, WdT_bf);
    k_xspa<<<dim3(16, 12, 4), 256, 0, stream>>>(hist, hs, W_emb, b_emb, b_st, U1, T1, D1,
                                                W_g2, b_g2, b_dif, WstT_bf, WdT_bf, XT, out);
    dim3 dgrid(3, 16, 12);
    k_diff3<<<dgrid, 256, 0, stream>>>(S_bf, adjF, adjT, rs, cs, XT, 0, Z1);
    k_diff3<<<dgrid, 256, 0, stream>>>(S_bf, adjF, adjT, rs, cs, Z1, 1, Z2);
    k_zmfma<<<dim3(16, 12, 4), 256, 0, stream>>>(Z1, Z2, WdT_bf, out);
}